// Round 5
// baseline (26020.578 us; speedup 1.0000x reference)
//
#include <hip/hip_runtime.h>

#define D 64
#define NB 8          // source blocks == XCDs
#define BPB 11264     // nodes per source block (8*11264 = 90112 >= 90000); 2.75 MB of y per block
#define RPW 22        // rows per wave: 1024 WGs * 4 waves * 22 = 90112 rows, single-shot resident

typedef float v4f __attribute__((ext_vector_type(4)));

// ---- setup: blocked-CSR build ----------------------------------------------

__global__ void blkcnt_kernel(const int* __restrict__ row, const int* __restrict__ col,
                              int* __restrict__ cnt, int N_, int E_) {
    int e = blockIdx.x * blockDim.x + threadIdx.x;
    if (e < E_) {
        int s = row[e];
        int d = col[e];
        int b = s / BPB;
        atomicAdd(&cnt[b * N_ + d], 1);
    }
}

__global__ void dinv_kernel(const int* __restrict__ cnt, float* __restrict__ dinv,
                            float* __restrict__ dinv2, int N_) {
    int d = blockIdx.x * blockDim.x + threadIdx.x;
    if (d < N_) {
        int s = 0;
#pragma unroll
        for (int b = 0; b < NB; ++b) s += cnt[b * N_ + d];
        float r = (s > 0) ? (1.0f / sqrtf((float)s)) : 0.0f;
        dinv[d] = r;
        dinv2[d] = r * r;
    }
}

// Single-workgroup exclusive scan (used only for the 704 chunk sums).
__global__ __launch_bounds__(1024) void scan_kernel(const int* __restrict__ in,
                                                    int* __restrict__ out, int n) {
    __shared__ int wsum[16];
    const int tid = threadIdx.x;
    const int lane = tid & 63;
    const int w = tid >> 6;
    int carry = 0;
    for (int base = 0; base < n; base += 1024) {
        int i = base + tid;
        int v = (i < n) ? in[i] : 0;
        int x = v;
#pragma unroll
        for (int off = 1; off < 64; off <<= 1) {
            int y = __shfl_up(x, off);
            if (lane >= off) x += y;
        }
        if (lane == 63) wsum[w] = x;
        __syncthreads();
        if (w == 0 && lane < 16) {
            int s = wsum[lane];
#pragma unroll
            for (int off = 1; off < 16; off <<= 1) {
                int y = __shfl_up(s, off);
                if (lane >= off) s += y;
            }
            wsum[lane] = s;
        }
        __syncthreads();
        int pref = (w > 0) ? wsum[w - 1] : 0;
        if (i < n) out[i] = carry + pref + (x - v);
        carry += wsum[15];
        __syncthreads();
    }
    if (tid == 0) out[n] = carry;
}

__global__ __launch_bounds__(256) void chunk_sum_kernel(const int* __restrict__ v,
                                                        int* __restrict__ csum, int n) {
    int base = blockIdx.x * 1024;
    int tid = threadIdx.x;
    int s = 0;
#pragma unroll
    for (int k = 0; k < 4; ++k) {
        int i = base + tid + k * 256;
        if (i < n) s += v[i];
    }
#pragma unroll
    for (int off = 32; off; off >>= 1) s += __shfl_down(s, off);
    __shared__ int ws[4];
    int lane = tid & 63, w = tid >> 6;
    if (lane == 0) ws[w] = s;
    __syncthreads();
    if (tid == 0) csum[blockIdx.x] = ws[0] + ws[1] + ws[2] + ws[3];
}

__global__ __launch_bounds__(256) void chunk_scan_kernel(const int* __restrict__ v,
                                                         const int* __restrict__ coff,
                                                         int* __restrict__ out, int n, int total) {
    int base = blockIdx.x * 1024;
    int tid = threadIdx.x;
    int lane = tid & 63, w = tid >> 6;
    int idx0 = base + tid * 4;
    int a0 = (idx0 + 0 < n) ? v[idx0 + 0] : 0;
    int a1 = (idx0 + 1 < n) ? v[idx0 + 1] : 0;
    int a2 = (idx0 + 2 < n) ? v[idx0 + 2] : 0;
    int a3 = (idx0 + 3 < n) ? v[idx0 + 3] : 0;
    int ts = a0 + a1 + a2 + a3;
    int x = ts;
#pragma unroll
    for (int off = 1; off < 64; off <<= 1) {
        int y = __shfl_up(x, off);
        if (lane >= off) x += y;
    }
    __shared__ int ws[4];
    if (lane == 63) ws[w] = x;
    __syncthreads();
    int wpref = 0;
    if (w > 0) wpref += ws[0];
    if (w > 1) wpref += ws[1];
    if (w > 2) wpref += ws[2];
    int off0 = coff[blockIdx.x] + wpref + (x - ts);
    if (idx0 + 0 < n) out[idx0 + 0] = off0;
    if (idx0 + 1 < n) out[idx0 + 1] = off0 + a0;
    if (idx0 + 2 < n) out[idx0 + 2] = off0 + a0 + a1;
    if (idx0 + 3 < n) out[idx0 + 3] = off0 + a0 + a1 + a2;
    if (blockIdx.x == 0 && tid == 0) out[n] = total;
}

__global__ void scatter_blk_kernel(const int* __restrict__ row, const int* __restrict__ col,
                                   const int* __restrict__ blk_ptr, int* __restrict__ cursor,
                                   int* __restrict__ csr_src, int N_, int E_) {
    int e = blockIdx.x * blockDim.x + threadIdx.x;
    if (e < E_) {
        int s = row[e];
        int d = col[e];
        int b = s / BPB;
        int j = b * N_ + d;
        int pos = blk_ptr[j] + atomicAdd(&cursor[j], 1);
        csr_src[pos] = s;
    }
}

// y = dinv * emb; acc(out) = emb
__global__ void init_kernel(const v4f* __restrict__ emb, const float* __restrict__ dinv,
                            v4f* __restrict__ y, v4f* __restrict__ out, int N_) {
    int i = blockIdx.x * blockDim.x + threadIdx.x;
    if (i < N_ * 16) {
        v4f v = emb[i];
        out[i] = v;
        y[i] = v * dinv[i >> 4];
    }
}

// ---- the layer kernel ------------------------------------------------------
// Single-shot resident grid (1024 WGs = 4/CU at <=128 VGPR). Each wave owns 22
// rows; accumulators live in VGPRs across all 8 source-block phases. Phase order
// b = (blockIdx%8 + p)%8 keeps each XCD gathering from one 2.75 MB L2-resident
// block. No per-edge weights (y-trick): x_new = dinv[d]*S, y_new = dinv2[d]*S.
__global__ __launch_bounds__(256, 4) void spmm_phased_kernel(
    const v4f* __restrict__ y_in, v4f* __restrict__ y_out, v4f* __restrict__ acc,
    const int* __restrict__ blk_ptr, const int* __restrict__ csr_src,
    const float* __restrict__ dinv, const float* __restrict__ dinv2, int n) {
    const int wid = (blockIdx.x << 2) | (threadIdx.x >> 6);
    const int lane = threadIdx.x & 63;
    const int g = lane >> 4;   // edge slot 0..3
    const int t = lane & 15;   // v4f slot within the 64-dim row
    const int r0 = wid * RPW;
    if (r0 >= n) return;

    v4f s[RPW];
#pragma unroll
    for (int i = 0; i < RPW; ++i) s[i] = 0.f;

    const int xcd = blockIdx.x & 7;
#pragma unroll 1
    for (int p = 0; p < NB; ++p) {
        const int b = (xcd + p) & 7;
        const int* __restrict__ bp = blk_ptr + (size_t)b * n + r0;
#pragma unroll
        for (int i = 0; i < RPW; ++i) {
            if (r0 + i < n) {
                int beg = bp[i], end = bp[i + 1];
                for (int e = beg + g; e < end; e += 4) {
                    int src = __builtin_nontemporal_load(&csr_src[e]);
                    s[i] += y_in[src * 16 + t];
                }
            }
        }
    }

#pragma unroll
    for (int i = 0; i < RPW; ++i) {
        int r = r0 + i;
        if (r >= n) break;   // wave-uniform
        v4f v = s[i];
        v.x += __shfl_xor(v.x, 16); v.x += __shfl_xor(v.x, 32);
        v.y += __shfl_xor(v.y, 16); v.y += __shfl_xor(v.y, 32);
        v.z += __shfl_xor(v.z, 16); v.z += __shfl_xor(v.z, 32);
        v.w += __shfl_xor(v.w, 16); v.w += __shfl_xor(v.w, 32);
        if (g == 0) {
            float di = dinv[r], di2 = dinv2[r];
            int o = r * 16 + t;
            y_out[o] = v * di2;
            v4f a = __builtin_nontemporal_load(&acc[o]);
            __builtin_nontemporal_store(a + v * di, &acc[o]);
        }
    }
}

__global__ void scale_kernel(v4f* __restrict__ out, float f, int n4) {
    int i = blockIdx.x * blockDim.x + threadIdx.x;
    if (i < n4) out[i] = out[i] * f;
}

// ---- host ------------------------------------------------------------------

extern "C" void kernel_launch(void* const* d_in, const int* in_sizes, int n_in,
                              void* d_out, int out_size, void* d_ws, size_t ws_size,
                              hipStream_t stream) {
    const float* emb = (const float*)d_in[0];
    const int* eidx = (const int*)d_in[1];
    const int N = in_sizes[0] / D;   // 90000
    const int E = in_sizes[1] / 2;   // 3000000
    const int L = 100;
    const int* row = eidx;       // edge_index[0] (src)
    const int* col = eidx + E;   // edge_index[1] (dst)
    const int n2 = NB * N;       // 720000 buckets

    size_t off = 0;
    auto alloc = [&](size_t bytes) -> void* {
        void* p = (char*)d_ws + off;
        off += (bytes + 255) & ~(size_t)255;
        return p;
    };
    int*   cnt     = (int*)alloc((size_t)n2 * 4);
    int*   cursor  = (int*)alloc((size_t)n2 * 4);
    int*   blk_ptr = (int*)alloc((size_t)(n2 + 1) * 4);
    int*   csumA   = (int*)alloc(1028 * 4);
    int*   csumB   = (int*)alloc(1032 * 4);
    float* dinv    = (float*)alloc((size_t)N * 4);
    float* dinv2   = (float*)alloc((size_t)N * 4);
    int*   csr_src = (int*)alloc((size_t)E * 4);
    float* yA      = (float*)alloc((size_t)N * D * 4);
    float* yB      = (float*)alloc((size_t)N * D * 4);

    hipMemsetAsync(cnt, 0, (size_t)n2 * 4, stream);
    hipMemsetAsync(cursor, 0, (size_t)n2 * 4, stream);

    blkcnt_kernel<<<(E + 255) / 256, 256, 0, stream>>>(row, col, cnt, N, E);
    dinv_kernel<<<(N + 255) / 256, 256, 0, stream>>>(cnt, dinv, dinv2, N);

    const int nChunks = (n2 + 1023) / 1024;   // 704
    chunk_sum_kernel<<<nChunks, 256, 0, stream>>>(cnt, csumA, n2);
    scan_kernel<<<1, 1024, 0, stream>>>(csumA, csumB, nChunks);
    chunk_scan_kernel<<<nChunks, 256, 0, stream>>>(cnt, csumB, blk_ptr, n2, E);

    scatter_blk_kernel<<<(E + 255) / 256, 256, 0, stream>>>(row, col, blk_ptr, cursor,
                                                            csr_src, N, E);

    float* out = (float*)d_out;
    const int n4 = N * 16;
    init_kernel<<<(n4 + 255) / 256, 256, 0, stream>>>((const v4f*)emb, dinv,
                                                      (v4f*)yA, (v4f*)out, N);

    const v4f* yin = (const v4f*)yA;
    v4f* yout = (v4f*)yB;
    for (int l = 0; l < L; ++l) {
        spmm_phased_kernel<<<1024, 256, 0, stream>>>(yin, yout, (v4f*)out,
                                                     blk_ptr, csr_src, dinv, dinv2, N);
        const v4f* tmp = yout;
        yout = (yout == (v4f*)yA) ? (v4f*)yB : (v4f*)yA;
        yin = tmp;
    }

    scale_kernel<<<(n4 + 255) / 256, 256, 0, stream>>>((v4f*)out, 1.0f / (float)(L + 1), n4);
}

// Round 6
// 17269.939 us; speedup vs baseline: 1.5067x; 1.5067x over previous
//
#include <hip/hip_runtime.h>

#define D 64
#define RPQ 8   // rows per wave in the spmm kernel

typedef float v4f __attribute__((ext_vector_type(4)));

// ---- setup -----------------------------------------------------------------

__global__ void degree_kernel(const int* __restrict__ col, int* __restrict__ deg, int E_) {
    int e = blockIdx.x * blockDim.x + threadIdx.x;
    if (e < E_) atomicAdd(&deg[col[e]], 1);
}

__global__ void dinv_kernel(const int* __restrict__ deg, float* __restrict__ dinv,
                            float* __restrict__ dinv2, int n) {
    int i = blockIdx.x * blockDim.x + threadIdx.x;
    if (i < n) {
        int d = deg[i];
        float r = (d > 0) ? (1.0f / sqrtf((float)d)) : 0.0f;
        dinv[i] = r;
        dinv2[i] = r * r;
    }
}

// Single-workgroup exclusive scan over N elements (runs once per call).
__global__ __launch_bounds__(1024) void scan_kernel(const int* __restrict__ in,
                                                    int* __restrict__ out, int n) {
    __shared__ int wsum[16];
    const int tid = threadIdx.x;
    const int lane = tid & 63;
    const int w = tid >> 6;
    int carry = 0;
    for (int base = 0; base < n; base += 1024) {
        int i = base + tid;
        int v = (i < n) ? in[i] : 0;
        int x = v;
#pragma unroll
        for (int off = 1; off < 64; off <<= 1) {
            int y = __shfl_up(x, off);
            if (lane >= off) x += y;
        }
        if (lane == 63) wsum[w] = x;
        __syncthreads();
        if (w == 0 && lane < 16) {
            int s = wsum[lane];
#pragma unroll
            for (int off = 1; off < 16; off <<= 1) {
                int y = __shfl_up(s, off);
                if (lane >= off) s += y;
            }
            wsum[lane] = s;
        }
        __syncthreads();
        int pref = (w > 0) ? wsum[w - 1] : 0;
        if (i < n) out[i] = carry + pref + (x - v);
        carry += wsum[15];
        __syncthreads();
    }
    if (tid == 0) out[n] = carry;
}

__global__ void scatter_kernel(const int* __restrict__ row, const int* __restrict__ col,
                               const int* __restrict__ row_ptr, int* __restrict__ cursor,
                               int* __restrict__ csr_src, int E_) {
    int e = blockIdx.x * blockDim.x + threadIdx.x;
    if (e < E_) {
        int s = row[e];
        int d = col[e];
        int pos = row_ptr[d] + atomicAdd(&cursor[d], 1);
        csr_src[pos] = s;
    }
}

// emb [node][64] -> quarter-major y[q][node][16] * dinv, acc[q][node][16] = emb
__global__ void init_kernel(const v4f* __restrict__ emb, const float* __restrict__ dinv,
                            v4f* __restrict__ y, v4f* __restrict__ acc, int n) {
    int i = blockIdx.x * blockDim.x + threadIdx.x;
    if (i >= n * 16) return;
    int node = i >> 4;
    int j = i & 15;
    int q = j >> 2;
    int t = j & 3;
    v4f v = emb[i];
    size_t o = (size_t)q * n * 4 + (size_t)node * 4 + t;
    acc[o] = v;
    y[o] = v * dinv[node];
}

// quarter-major acc -> row-major out, scaled
__global__ void final_kernel(const v4f* __restrict__ acc, v4f* __restrict__ out,
                             float f, int n) {
    int i = blockIdx.x * blockDim.x + threadIdx.x;
    if (i >= n * 16) return;
    int node = i >> 4;
    int j = i & 15;
    int q = j >> 2;
    int t = j & 3;
    out[i] = acc[(size_t)q * n * 4 + (size_t)node * 4 + t] * f;
}

// ---- the layer kernel ------------------------------------------------------
// quarter q = blockIdx&3 (blockIdx%8 -> XCD round-robin => quarter q is served
// only by XCDs q and q+4; the 5.76 MB quarter table stays ~L2-resident there).
// Wave owns 8 full rows; 16 edge-slots x 4 lanes x float4 (64 B = 1 line per
// edge). Straight-line predicated steps: inactive slots load csr_src[0] and
// multiply by 0 — no exec masking, so 8+ gathers stay in flight per step.
__global__ __launch_bounds__(256) void spmm_q_kernel(
    const v4f* __restrict__ y_in, v4f* __restrict__ y_out, v4f* __restrict__ acc,
    const int* __restrict__ row_ptr, const int* __restrict__ csr_src,
    const float* __restrict__ dinv, const float* __restrict__ dinv2, int n) {
    const int q = blockIdx.x & 3;
    const int wave = threadIdx.x >> 6;
    const int lane = threadIdx.x & 63;
    const int slot = lane >> 2;   // edge slot 0..15
    const int t = lane & 3;       // v4f index within the 16-float quarter row
    const int r0 = ((blockIdx.x >> 2) * 4 + wave) * RPQ;
    if (r0 >= n) return;
    const v4f* __restrict__ yq_in = y_in + (size_t)q * n * 4;
    v4f* __restrict__ yq_out = y_out + (size_t)q * n * 4;
    v4f* __restrict__ accq = acc + (size_t)q * n * 4;

    int rp = row_ptr[min(r0 + lane, n)];
    int fin[RPQ], cur[RPQ];
    int maxlen = 0;
#pragma unroll
    for (int i = 0; i < RPQ; ++i) {
        int b = __shfl(rp, i);
        fin[i] = __shfl(rp, i + 1);
        maxlen = max(maxlen, fin[i] - b);
        cur[i] = b + slot;
    }
    v4f s[RPQ];
#pragma unroll
    for (int i = 0; i < RPQ; ++i) s[i] = 0.f;

    const int kmax = (maxlen + 15) >> 4;
    for (int k = 0; k < kmax; ++k) {
#pragma unroll
        for (int i = 0; i < RPQ; ++i) {
            bool act = cur[i] < fin[i];
            int idx = act ? cur[i] : 0;
            float w = act ? 1.0f : 0.0f;
            int src = __builtin_nontemporal_load(&csr_src[idx]);
            v4f v = yq_in[(size_t)src * 4 + t];
            s[i] += w * v;
            cur[i] += 16;
        }
    }

#pragma unroll
    for (int i = 0; i < RPQ; ++i) {
        v4f v = s[i];
#pragma unroll
        for (int off = 4; off < 64; off <<= 1) {
            v.x += __shfl_xor(v.x, off);
            v.y += __shfl_xor(v.y, off);
            v.z += __shfl_xor(v.z, off);
            v.w += __shfl_xor(v.w, off);
        }
        int r = r0 + i;
        if (lane < 4 && r < n) {
            float di = dinv[r], di2 = dinv2[r];
            size_t o = (size_t)r * 4 + t;
            yq_out[o] = v * di2;                     // plain store: must stay in L2
            v4f a = __builtin_nontemporal_load(&accq[o]);
            __builtin_nontemporal_store(a + v * di, &accq[o]);
        }
    }
}

// ---- host ------------------------------------------------------------------

extern "C" void kernel_launch(void* const* d_in, const int* in_sizes, int n_in,
                              void* d_out, int out_size, void* d_ws, size_t ws_size,
                              hipStream_t stream) {
    const float* emb = (const float*)d_in[0];
    const int* eidx = (const int*)d_in[1];
    const int N = in_sizes[0] / D;   // 90000
    const int E = in_sizes[1] / 2;   // 3000000
    const int L = 100;
    const int* row = eidx;       // edge_index[0] (src)
    const int* col = eidx + E;   // edge_index[1] (dst)

    size_t off = 0;
    auto alloc = [&](size_t bytes) -> void* {
        void* p = (char*)d_ws + off;
        off += (bytes + 255) & ~(size_t)255;
        return p;
    };
    int*   deg     = (int*)alloc((size_t)N * 4);
    float* dinv    = (float*)alloc((size_t)N * 4);
    float* dinv2   = (float*)alloc((size_t)N * 4);
    int*   row_ptr = (int*)alloc((size_t)(N + 1) * 4);
    int*   cursor  = (int*)alloc((size_t)N * 4);
    int*   csr_src = (int*)alloc((size_t)(E + 64) * 4);
    float* yA      = (float*)alloc((size_t)N * D * 4);
    float* yB      = (float*)alloc((size_t)N * D * 4);
    float* accq    = (float*)alloc((size_t)N * D * 4);

    hipMemsetAsync(deg, 0, (size_t)N * 4, stream);
    hipMemsetAsync(cursor, 0, (size_t)N * 4, stream);

    degree_kernel<<<(E + 255) / 256, 256, 0, stream>>>(col, deg, E);
    dinv_kernel<<<(N + 255) / 256, 256, 0, stream>>>(deg, dinv, dinv2, N);
    scan_kernel<<<1, 1024, 0, stream>>>(deg, row_ptr, N);
    scatter_kernel<<<(E + 255) / 256, 256, 0, stream>>>(row, col, row_ptr, cursor,
                                                        csr_src, E);

    const int nv4 = N * 16;
    init_kernel<<<(nv4 + 255) / 256, 256, 0, stream>>>((const v4f*)emb, dinv,
                                                       (v4f*)yA, (v4f*)accq, N);

    // 4 waves/WG x 8 rows = 32 rows per WG per quarter; grid interleaves quarters
    const int nWGq = (N + 31) / 32;
    const int grid = nWGq * 4;
    const v4f* yin = (const v4f*)yA;
    v4f* yout = (v4f*)yB;
    for (int l = 0; l < L; ++l) {
        spmm_q_kernel<<<grid, 256, 0, stream>>>(yin, yout, (v4f*)accq,
                                                row_ptr, csr_src, dinv, dinv2, N);
        const v4f* tmp = yout;
        yout = (yout == (v4f*)yA) ? (v4f*)yB : (v4f*)yA;
        yin = tmp;
    }

    final_kernel<<<(nv4 + 255) / 256, 256, 0, stream>>>((const v4f*)accq, (v4f*)d_out,
                                                        1.0f / (float)(L + 1), N);
}